// Round 1
// baseline (305.171 us; speedup 1.0000x reference)
//
#include <hip/hip_runtime.h>
#include <cstdint>
#include <cstddef>

typedef unsigned short u16;
typedef unsigned int u32;
typedef __attribute__((ext_vector_type(8))) short short8;
typedef __attribute__((ext_vector_type(4))) float f32x4;

static __device__ __forceinline__ u16 f2bf(float x) {
    u32 u = __builtin_bit_cast(u32, x);
    u += 0x7FFFu + ((u >> 16) & 1u);
    return (u16)(u >> 16);
}

// ---------- weight transpose + f32->bf16 : dst[C][R] = src[R][C] ----------
__global__ __launch_bounds__(256) void wtrans_kernel(
    const float* __restrict__ src, u16* __restrict__ dst, int R, int C)
{
    __shared__ float t[32][33];
    int c0 = blockIdx.x * 32, r0 = blockIdx.y * 32;
    int tx = threadIdx.x & 31, ty = threadIdx.x >> 5;
    #pragma unroll
    for (int rr = 0; rr < 32; rr += 8)
        t[ty + rr][tx] = src[(size_t)(r0 + ty + rr) * C + c0 + tx];
    __syncthreads();
    #pragma unroll
    for (int rr = 0; rr < 32; rr += 8)
        dst[(size_t)(c0 + ty + rr) * R + r0 + tx] = f2bf(t[tx][ty + rr]);
}

// ---------- alpha transpose f32: at[b][i][j] = a[b][j][i] ----------
__global__ __launch_bounds__(256) void atrans_kernel(
    const float* __restrict__ a, float* __restrict__ at)
{
    __shared__ float t[32][33];
    int b = blockIdx.z;
    int i0 = blockIdx.y * 32, j0 = blockIdx.x * 32;
    int tx = threadIdx.x & 31, ty = threadIdx.x >> 5;
    const float* ab = a + ((size_t)b << 20);
    float* atb = at + ((size_t)b << 20);
    #pragma unroll
    for (int rr = 0; rr < 32; rr += 8)
        t[ty + rr][tx] = ab[(size_t)(j0 + ty + rr) * 1024 + i0 + tx];
    __syncthreads();
    #pragma unroll
    for (int rr = 0; rr < 32; rr += 8)
        atb[(size_t)(i0 + ty + rr) * 1024 + j0 + tx] = t[tx][ty + rr];
}

// ---------- fused LayerNorm for x and ORquery, f32 -> bf16 ----------
__global__ __launch_bounds__(64) void ln_kernel(
    const float* __restrict__ x, const float* __restrict__ orqy,
    const float* __restrict__ lw, const float* __restrict__ lb,
    u16* __restrict__ xn, u16* __restrict__ orqn)
{
    int row = blockIdx.x; // 0..16383
    const float* src;
    u16* dst;
    if (row < 8192) { src = x + (size_t)row * 512; dst = xn + (size_t)row * 512; }
    else { src = orqy + (size_t)(row - 8192) * 512; dst = orqn + (size_t)(row - 8192) * 512; }
    int lane = threadIdx.x;
    float4 a = *(const float4*)(src + lane * 8);
    float4 b = *(const float4*)(src + lane * 8 + 4);
    float s = a.x + a.y + a.z + a.w + b.x + b.y + b.z + b.w;
    float q = a.x*a.x + a.y*a.y + a.z*a.z + a.w*a.w
            + b.x*b.x + b.y*b.y + b.z*b.z + b.w*b.w;
    #pragma unroll
    for (int off = 32; off >= 1; off >>= 1) {
        s += __shfl_xor(s, off);
        q += __shfl_xor(q, off);
    }
    float mu = s * (1.0f / 512.0f);
    float var = q * (1.0f / 512.0f) - mu * mu;
    float rs = 1.0f / sqrtf(var + 1e-5f);
    float4 w0 = *(const float4*)(lw + lane * 8);
    float4 w1 = *(const float4*)(lw + lane * 8 + 4);
    float4 b0 = *(const float4*)(lb + lane * 8);
    float4 b1 = *(const float4*)(lb + lane * 8 + 4);
    union { u16 h[8]; uint4 v; } ou;
    ou.h[0] = f2bf((a.x - mu) * rs * w0.x + b0.x);
    ou.h[1] = f2bf((a.y - mu) * rs * w0.y + b0.y);
    ou.h[2] = f2bf((a.z - mu) * rs * w0.z + b0.z);
    ou.h[3] = f2bf((a.w - mu) * rs * w0.w + b0.w);
    ou.h[4] = f2bf((b.x - mu) * rs * w1.x + b1.x);
    ou.h[5] = f2bf((b.y - mu) * rs * w1.y + b1.y);
    ou.h[6] = f2bf((b.z - mu) * rs * w1.z + b1.z);
    ou.h[7] = f2bf((b.w - mu) * rs * w1.w + b1.w);
    *(uint4*)(dst + lane * 8) = ou.v;
}

// ---------- bf16 MFMA GEMM: C[8192,N] = A[8192,K] @ Bt[N,K]^T ----------
// mode 0: scatter to q/k/v [B][H][N][64] bf16 (N=1536)
// mode 1: scatter to oq    [B][H][N][64] bf16 (N=512)
// mode 2: write f32 row-major to of (N=512)
__global__ __launch_bounds__(256) void gemm_kernel(
    const u16* __restrict__ A, const u16* __restrict__ Bt,
    int N, int K, int mode,
    u16* __restrict__ oq, u16* __restrict__ ok, u16* __restrict__ ov,
    float* __restrict__ of)
{
    __shared__ u16 As[128][40];
    __shared__ u16 Bs[128][40];
    int m0 = blockIdx.y * 128, n0 = blockIdx.x * 128;
    int tid = threadIdx.x;
    int w = tid >> 6, lane = tid & 63;
    int lo = lane & 15, hi = lane >> 4;
    int wm = (w >> 1) * 64, wn = (w & 1) * 64;
    f32x4 acc[4][4] = {};
    int nk = K >> 5;
    for (int kt = 0; kt < nk; ++kt) {
        #pragma unroll
        for (int rep = 0; rep < 2; ++rep) {
            int c = tid + rep * 256;
            int row = c >> 2, cc = (c & 3) * 8;
            *(uint4*)&As[row][cc] = *(const uint4*)&A[(size_t)(m0 + row) * K + kt * 32 + cc];
            *(uint4*)&Bs[row][cc] = *(const uint4*)&Bt[(size_t)(n0 + row) * K + kt * 32 + cc];
        }
        __syncthreads();
        short8 af[4], bfr[4];
        #pragma unroll
        for (int mf = 0; mf < 4; ++mf) af[mf] = *(const short8*)&As[wm + mf * 16 + lo][hi * 8];
        #pragma unroll
        for (int nf = 0; nf < 4; ++nf) bfr[nf] = *(const short8*)&Bs[wn + nf * 16 + lo][hi * 8];
        #pragma unroll
        for (int mf = 0; mf < 4; ++mf)
            #pragma unroll
            for (int nf = 0; nf < 4; ++nf)
                acc[mf][nf] = __builtin_amdgcn_mfma_f32_16x16x32_bf16(af[mf], bfr[nf], acc[mf][nf], 0, 0, 0);
        __syncthreads();
    }
    #pragma unroll
    for (int mf = 0; mf < 4; ++mf) {
        #pragma unroll
        for (int nf = 0; nf < 4; ++nf) {
            #pragma unroll
            for (int r = 0; r < 4; ++r) {
                int row = m0 + wm + mf * 16 + hi * 4 + r;
                int col = n0 + wn + nf * 16 + lo;
                float val = acc[mf][nf][r];
                if (mode == 2) {
                    of[(size_t)row * N + col] = val;
                } else {
                    u16 bv = f2bf(val);
                    int bb = row >> 10, i = row & 1023;
                    int which = col >> 9;
                    int h = (col >> 6) & 7;
                    int d = col & 63;
                    size_t idx = (((size_t)bb * 8 + h) * 1024 + i) * 64 + d;
                    if (mode == 1) oq[idx] = bv;
                    else (which == 0 ? oq : (which == 1 ? ok : ov))[idx] = bv;
                }
            }
        }
    }
}

// ---------- flash-style MFMA attention ----------
// Q,K,V: [B*H][1024][64] bf16. out: [B][1024][512] bf16 (merged heads).
// orMode: zero diagonal logits, multiply by (1 - alphaT[b][i][j]).
__global__ __launch_bounds__(256) void attn_kernel(
    const u16* __restrict__ Q, const u16* __restrict__ Kk, const u16* __restrict__ V,
    const float* __restrict__ alphaT,
    u16* __restrict__ out, int orMode)
{
    __shared__ u16 Qs[64][72];
    __shared__ u16 Ks[64][72];
    __shared__ u16 Vt[64][72];
    __shared__ u16 Ps[4][16][72];
    int it = blockIdx.x;          // i-tile 0..15
    int bh = blockIdx.y;          // 0..63
    int b = bh >> 3, h = bh & 7;
    int i0 = it * 64;
    int tid = threadIdx.x;
    int w = tid >> 6, lane = tid & 63;
    int lo = lane & 15, hi = lane >> 4;
    const u16* Qb = Q + ((size_t)bh * 1024 + i0) * 64;
    const u16* Kb = Kk + (size_t)bh * 1024 * 64;
    const u16* Vb = V + (size_t)bh * 1024 * 64;

    // stage Q tile
    #pragma unroll
    for (int rep = 0; rep < 2; ++rep) {
        int c = tid + rep * 256;
        int row = c >> 3, cc = (c & 7) * 8;
        *(uint4*)&Qs[row][cc] = *(const uint4*)&Qb[row * 64 + cc];
    }
    __syncthreads();
    short8 qf0 = *(const short8*)&Qs[w * 16 + lo][hi * 8];
    short8 qf1 = *(const short8*)&Qs[w * 16 + lo][32 + hi * 8];

    f32x4 o[4] = {};
    float m_r[4], l_r[4];
    #pragma unroll
    for (int r = 0; r < 4; ++r) { m_r[r] = -1e30f; l_r[r] = 0.0f; }

    for (int jt = 0; jt < 16; ++jt) {
        int j0 = jt * 64;
        // stage K tile (row-major) and V tile (transposed)
        #pragma unroll
        for (int rep = 0; rep < 2; ++rep) {
            int c = tid + rep * 256;
            int row = c >> 3, cc = (c & 7) * 8;
            *(uint4*)&Ks[row][cc] = *(const uint4*)&Kb[(size_t)(j0 + row) * 64 + cc];
            uint4 pv = *(const uint4*)&Vb[(size_t)(j0 + row) * 64 + cc];
            const u16* pvs = (const u16*)&pv;
            #pragma unroll
            for (int e = 0; e < 8; ++e) Vt[cc + e][row] = pvs[e];
        }
        __syncthreads();

        // S = Q K^T
        f32x4 s[4];
        #pragma unroll
        for (int jf = 0; jf < 4; ++jf) {
            f32x4 z = {};
            short8 kf0 = *(const short8*)&Ks[jf * 16 + lo][hi * 8];
            short8 kf1 = *(const short8*)&Ks[jf * 16 + lo][32 + hi * 8];
            z = __builtin_amdgcn_mfma_f32_16x16x32_bf16(qf0, kf0, z, 0, 0, 0);
            z = __builtin_amdgcn_mfma_f32_16x16x32_bf16(qf1, kf1, z, 0, 0, 0);
            s[jf] = z;
        }
        // scale + OR modifications
        #pragma unroll
        for (int jf = 0; jf < 4; ++jf) {
            #pragma unroll
            for (int r = 0; r < 4; ++r) {
                float sv = s[jf][r] * 0.125f;
                if (orMode) {
                    int ig = i0 + w * 16 + hi * 4 + r;
                    int jg = j0 + jf * 16 + lo;
                    if (ig == jg) sv = 0.0f;
                    sv *= (1.0f - alphaT[((size_t)b << 20) + ((size_t)ig << 10) + jg]);
                }
                s[jf][r] = sv;
            }
        }
        // online softmax per row (rows hi*4+r, reduce across 16-lane group)
        float scl[4];
        #pragma unroll
        for (int r = 0; r < 4; ++r) {
            float mx = fmaxf(fmaxf(s[0][r], s[1][r]), fmaxf(s[2][r], s[3][r]));
            #pragma unroll
            for (int msk = 8; msk >= 1; msk >>= 1) mx = fmaxf(mx, __shfl_xor(mx, msk));
            float mn = fmaxf(m_r[r], mx);
            scl[r] = __expf(m_r[r] - mn);
            m_r[r] = mn;
            float ps = 0.0f;
            #pragma unroll
            for (int jf = 0; jf < 4; ++jf) {
                float p = __expf(s[jf][r] - mn);
                s[jf][r] = p;
                ps += p;
            }
            #pragma unroll
            for (int msk = 8; msk >= 1; msk >>= 1) ps += __shfl_xor(ps, msk);
            l_r[r] = l_r[r] * scl[r] + ps;
        }
        // rescale O
        #pragma unroll
        for (int df = 0; df < 4; ++df)
            #pragma unroll
            for (int r = 0; r < 4; ++r) o[df][r] *= scl[r];
        // P -> LDS (bf16)
        #pragma unroll
        for (int jf = 0; jf < 4; ++jf)
            #pragma unroll
            for (int r = 0; r < 4; ++r)
                Ps[w][hi * 4 + r][jf * 16 + lo] = f2bf(s[jf][r]);
        // O += P V
        short8 pa0 = *(const short8*)&Ps[w][lo][hi * 8];
        short8 pa1 = *(const short8*)&Ps[w][lo][32 + hi * 8];
        #pragma unroll
        for (int df = 0; df < 4; ++df) {
            short8 v0 = *(const short8*)&Vt[df * 16 + lo][hi * 8];
            short8 v1 = *(const short8*)&Vt[df * 16 + lo][32 + hi * 8];
            o[df] = __builtin_amdgcn_mfma_f32_16x16x32_bf16(pa0, v0, o[df], 0, 0, 0);
            o[df] = __builtin_amdgcn_mfma_f32_16x16x32_bf16(pa1, v1, o[df], 0, 0, 0);
        }
        __syncthreads();
    }
    // finalize + write
    #pragma unroll
    for (int r = 0; r < 4; ++r) l_r[r] = 1.0f / l_r[r];
    #pragma unroll
    for (int df = 0; df < 4; ++df) {
        #pragma unroll
        for (int r = 0; r < 4; ++r) {
            int ig = i0 + w * 16 + hi * 4 + r;
            out[((size_t)b * 1024 + ig) * 512 + h * 64 + df * 16 + lo] = f2bf(o[df][r] * l_r[r]);
        }
    }
}

extern "C" void kernel_launch(void* const* d_in, const int* in_sizes, int n_in,
                              void* d_out, int out_size, void* d_ws, size_t ws_size,
                              hipStream_t stream)
{
    const float* x     = (const float*)d_in[0];
    const float* orqy  = (const float*)d_in[1];
    const float* alpha = (const float*)d_in[2];
    const float* ln_w  = (const float*)d_in[3];
    const float* ln_b  = (const float*)d_in[4];
    const float* w_qkv = (const float*)d_in[5];
    const float* w_orq = (const float*)d_in[6];
    const float* w_out = (const float*)d_in[7];
    float* outp = (float*)d_out;

    char* base = (char*)d_ws;
    size_t off = 0;
    auto alloc = [&](size_t bytes) -> char* {
        char* r = base + off;
        off += (bytes + 255) & ~(size_t)255;
        return r;
    };
    const size_t RC = 8192ull * 512 * 2; // one [8192,512] bf16 buffer
    u16* xn       = (u16*)alloc(RC);
    u16* orqn     = (u16*)alloc(RC);
    u16* qb       = (u16*)alloc(RC);
    u16* kb       = (u16*)alloc(RC);
    u16* vb       = (u16*)alloc(RC);
    u16* orqb     = (u16*)alloc(RC);
    u16* attout   = (u16*)alloc(RC);
    u16* orattout = (u16*)alloc(RC);
    u16* wqkvT    = (u16*)alloc(1536ull * 512 * 2);
    u16* worqT    = (u16*)alloc(512ull * 512 * 2);
    u16* woutT    = (u16*)alloc(512ull * 512 * 2);
    float* alphaT = (float*)alloc(8ull * 1024 * 1024 * 4);

    wtrans_kernel<<<dim3(48, 16), 256, 0, stream>>>(w_qkv, wqkvT, 512, 1536);
    wtrans_kernel<<<dim3(16, 16), 256, 0, stream>>>(w_orq, worqT, 512, 512);
    wtrans_kernel<<<dim3(16, 16), 256, 0, stream>>>(w_out, woutT, 512, 512);
    atrans_kernel<<<dim3(32, 32, 8), 256, 0, stream>>>(alpha, alphaT);
    ln_kernel<<<16384, 64, 0, stream>>>(x, orqy, ln_w, ln_b, xn, orqn);
    gemm_kernel<<<dim3(12, 64), 256, 0, stream>>>(xn, wqkvT, 1536, 512, 0, qb, kb, vb, nullptr);
    gemm_kernel<<<dim3(4, 64), 256, 0, stream>>>(orqn, worqT, 512, 512, 1, orqb, nullptr, nullptr, nullptr);
    attn_kernel<<<dim3(16, 64), 256, 0, stream>>>(qb, kb, vb, nullptr, attout, 0);
    attn_kernel<<<dim3(16, 64), 256, 0, stream>>>(orqb, kb, vb, alphaT, orattout, 1);
    gemm_kernel<<<dim3(4, 64), 256, 0, stream>>>(attout, woutT, 512, 512, 2, nullptr, nullptr, nullptr, outp);
    gemm_kernel<<<dim3(4, 64), 256, 0, stream>>>(orattout, woutT, 512, 512, 2, nullptr, nullptr, nullptr, outp + 8ull * 1024 * 512);
}

// Round 2
// 258.229 us; speedup vs baseline: 1.1818x; 1.1818x over previous
//
#include <hip/hip_runtime.h>
#include <cstdint>
#include <cstddef>

typedef unsigned short u16;
typedef unsigned int u32;
typedef __attribute__((ext_vector_type(8))) short short8;
typedef __attribute__((ext_vector_type(4))) float f32x4;

static __device__ __forceinline__ u16 f2bf(float x) {
    u32 u = __builtin_bit_cast(u32, x);
    u += 0x7FFFu + ((u >> 16) & 1u);
    return (u16)(u >> 16);
}

// swizzled u16 index of 16B block cb (0..7) in a 64-u16 row
#define SW(row, cb) (((row) * 64) + ((((cb) ^ ((row) & 7))) * 8))

// ---------- weight transpose + f32->bf16 : dst[C][R] = src[R][C] ----------
__global__ __launch_bounds__(256) void wtrans_kernel(
    const float* __restrict__ src, u16* __restrict__ dst, int R, int C)
{
    __shared__ float t[32][33];
    int c0 = blockIdx.x * 32, r0 = blockIdx.y * 32;
    int tx = threadIdx.x & 31, ty = threadIdx.x >> 5;
    #pragma unroll
    for (int rr = 0; rr < 32; rr += 8)
        t[ty + rr][tx] = src[(size_t)(r0 + ty + rr) * C + c0 + tx];
    __syncthreads();
    #pragma unroll
    for (int rr = 0; rr < 32; rr += 8)
        dst[(size_t)(c0 + ty + rr) * R + r0 + tx] = f2bf(t[tx][ty + rr]);
}

// ---------- alpha transpose f32: at[b][i][j] = a[b][j][i] ----------
__global__ __launch_bounds__(256) void atrans_kernel(
    const float* __restrict__ a, float* __restrict__ at)
{
    __shared__ float t[32][33];
    int b = blockIdx.z;
    int i0 = blockIdx.y * 32, j0 = blockIdx.x * 32;
    int tx = threadIdx.x & 31, ty = threadIdx.x >> 5;
    const float* ab = a + ((size_t)b << 20);
    float* atb = at + ((size_t)b << 20);
    #pragma unroll
    for (int rr = 0; rr < 32; rr += 8)
        t[ty + rr][tx] = ab[(size_t)(j0 + ty + rr) * 1024 + i0 + tx];
    __syncthreads();
    #pragma unroll
    for (int rr = 0; rr < 32; rr += 8)
        atb[(size_t)(i0 + ty + rr) * 1024 + j0 + tx] = t[tx][ty + rr];
}

// ---------- fused LayerNorm for x and ORquery, f32 -> bf16 ----------
__global__ __launch_bounds__(256) void ln_kernel(
    const float* __restrict__ x, const float* __restrict__ orqy,
    const float* __restrict__ lw, const float* __restrict__ lb,
    u16* __restrict__ xn, u16* __restrict__ orqn)
{
    int row = blockIdx.x * 4 + (threadIdx.x >> 6); // 0..16383
    const float* src;
    u16* dst;
    if (row < 8192) { src = x + (size_t)row * 512; dst = xn + (size_t)row * 512; }
    else { src = orqy + (size_t)(row - 8192) * 512; dst = orqn + (size_t)(row - 8192) * 512; }
    int lane = threadIdx.x & 63;
    float4 a = *(const float4*)(src + lane * 8);
    float4 b = *(const float4*)(src + lane * 8 + 4);
    float s = a.x + a.y + a.z + a.w + b.x + b.y + b.z + b.w;
    float q = a.x*a.x + a.y*a.y + a.z*a.z + a.w*a.w
            + b.x*b.x + b.y*b.y + b.z*b.z + b.w*b.w;
    #pragma unroll
    for (int off = 32; off >= 1; off >>= 1) {
        s += __shfl_xor(s, off);
        q += __shfl_xor(q, off);
    }
    float mu = s * (1.0f / 512.0f);
    float var = q * (1.0f / 512.0f) - mu * mu;
    float rs = 1.0f / sqrtf(var + 1e-5f);
    float4 w0 = *(const float4*)(lw + lane * 8);
    float4 w1 = *(const float4*)(lw + lane * 8 + 4);
    float4 b0 = *(const float4*)(lb + lane * 8);
    float4 b1 = *(const float4*)(lb + lane * 8 + 4);
    union { u16 h[8]; uint4 v; } ou;
    ou.h[0] = f2bf((a.x - mu) * rs * w0.x + b0.x);
    ou.h[1] = f2bf((a.y - mu) * rs * w0.y + b0.y);
    ou.h[2] = f2bf((a.z - mu) * rs * w0.z + b0.z);
    ou.h[3] = f2bf((a.w - mu) * rs * w0.w + b0.w);
    ou.h[4] = f2bf((b.x - mu) * rs * w1.x + b1.x);
    ou.h[5] = f2bf((b.y - mu) * rs * w1.y + b1.y);
    ou.h[6] = f2bf((b.z - mu) * rs * w1.z + b1.z);
    ou.h[7] = f2bf((b.w - mu) * rs * w1.w + b1.w);
    *(uint4*)(dst + lane * 8) = ou.v;
}

// ---------- bf16 MFMA GEMM: C[8192,N] = A[8192,K] @ Bt[N,K]^T ----------
// mode 0: scatter q/k to [B][H][N][64], V TRANSPOSED to [B][H][64][N] (N=1536)
// mode 1: scatter to oq  [B][H][N][64] bf16 (N=512)
// mode 2: write f32 row-major to of (N=512)
__global__ __launch_bounds__(256) void gemm_kernel(
    const u16* __restrict__ A, const u16* __restrict__ Bt,
    int N, int K, int mode,
    u16* __restrict__ oq, u16* __restrict__ ok, u16* __restrict__ ov,
    float* __restrict__ of)
{
    __shared__ u16 As[128][40];
    __shared__ u16 Bs[128][40];
    int m0 = blockIdx.y * 128, n0 = blockIdx.x * 128;
    int tid = threadIdx.x;
    int w = tid >> 6, lane = tid & 63;
    int lo = lane & 15, hi = lane >> 4;
    int wm = (w >> 1) * 64, wn = (w & 1) * 64;
    f32x4 acc[4][4] = {};
    int nk = K >> 5;
    for (int kt = 0; kt < nk; ++kt) {
        #pragma unroll
        for (int rep = 0; rep < 2; ++rep) {
            int c = tid + rep * 256;
            int row = c >> 2, cc = (c & 3) * 8;
            *(uint4*)&As[row][cc] = *(const uint4*)&A[(size_t)(m0 + row) * K + kt * 32 + cc];
            *(uint4*)&Bs[row][cc] = *(const uint4*)&Bt[(size_t)(n0 + row) * K + kt * 32 + cc];
        }
        __syncthreads();
        short8 af[4], bfr[4];
        #pragma unroll
        for (int mf = 0; mf < 4; ++mf) af[mf] = *(const short8*)&As[wm + mf * 16 + lo][hi * 8];
        #pragma unroll
        for (int nf = 0; nf < 4; ++nf) bfr[nf] = *(const short8*)&Bs[wn + nf * 16 + lo][hi * 8];
        #pragma unroll
        for (int mf = 0; mf < 4; ++mf)
            #pragma unroll
            for (int nf = 0; nf < 4; ++nf)
                acc[mf][nf] = __builtin_amdgcn_mfma_f32_16x16x32_bf16(af[mf], bfr[nf], acc[mf][nf], 0, 0, 0);
        __syncthreads();
    }
    #pragma unroll
    for (int mf = 0; mf < 4; ++mf) {
        #pragma unroll
        for (int nf = 0; nf < 4; ++nf) {
            #pragma unroll
            for (int r = 0; r < 4; ++r) {
                int row = m0 + wm + mf * 16 + hi * 4 + r;
                int col = n0 + wn + nf * 16 + lo;
                float val = acc[mf][nf][r];
                if (mode == 2) {
                    of[(size_t)row * N + col] = val;
                } else {
                    u16 bv = f2bf(val);
                    int bb = row >> 10, i = row & 1023;
                    int which = col >> 9;
                    int h = (col >> 6) & 7;
                    int d = col & 63;
                    if (mode == 0 && which == 2) {
                        // V transposed: [bh][64][1024]
                        ov[(((size_t)bb * 8 + h) * 64 + d) * 1024 + i] = bv;
                    } else {
                        size_t idx = (((size_t)bb * 8 + h) * 1024 + i) * 64 + d;
                        if (mode == 1) oq[idx] = bv;
                        else (which == 0 ? oq : ok)[idx] = bv;
                    }
                }
            }
        }
    }
}

// ---------- flash-style MFMA attention ----------
// Q: [B*H][1024][64] bf16. Vt: [B*H][64][1024] bf16 (pre-transposed).
// out: [B][1024][512] bf16 (merged heads).
__global__ __launch_bounds__(256) void attn_kernel(
    const u16* __restrict__ Q, const u16* __restrict__ Kk, const u16* __restrict__ Vt,
    const float* __restrict__ alphaT,
    u16* __restrict__ out, int orMode)
{
    __shared__ u16 Qs[64 * 64];
    __shared__ u16 Ks[64 * 64];
    __shared__ u16 Vs[64 * 64];
    __shared__ u16 Ps[4 * 16 * 64];
    // XCD swizzle: each XCD owns 8 consecutive bh (K/V fit its 4MB L2)
    int id = blockIdx.x;
    int sw = (id & 7) * 128 + (id >> 3);
    int bh = sw >> 4, it = sw & 15;
    int b = bh >> 3, h = bh & 7;
    int i0 = it * 64;
    int tid = threadIdx.x;
    int w = tid >> 6, lane = tid & 63;
    int lo = lane & 15, hi = lane >> 4;
    const u16* Qb = Q + ((size_t)bh * 1024 + i0) * 64;
    const u16* Kb = Kk + (size_t)bh * 1024 * 64;
    const u16* Vb = Vt + (size_t)bh * 64 * 1024;

    // stage Q tile (swizzled)
    #pragma unroll
    for (int rep = 0; rep < 2; ++rep) {
        int c = tid + rep * 256;
        int row = c >> 3, cb = c & 7;
        *(uint4*)&Qs[SW(row, cb)] = *(const uint4*)&Qb[row * 64 + cb * 8];
    }
    __syncthreads();
    short8 qf0 = *(const short8*)&Qs[SW(w * 16 + lo, hi)];
    short8 qf1 = *(const short8*)&Qs[SW(w * 16 + lo, 4 + hi)];

    f32x4 o[4] = {};
    float m_r[4], l_r[4];
    #pragma unroll
    for (int r = 0; r < 4; ++r) { m_r[r] = -1e30f; l_r[r] = 0.0f; }

    for (int jt = 0; jt < 16; ++jt) {
        int j0 = jt * 64;
        // stage K tile [64 j][64 d] and Vt tile [64 d][64 j], both swizzled
        #pragma unroll
        for (int rep = 0; rep < 2; ++rep) {
            int c = tid + rep * 256;
            int row = c >> 3, cb = c & 7;
            *(uint4*)&Ks[SW(row, cb)] = *(const uint4*)&Kb[(size_t)(j0 + row) * 64 + cb * 8];
            *(uint4*)&Vs[SW(row, cb)] = *(const uint4*)&Vb[(size_t)row * 1024 + j0 + cb * 8];
        }
        __syncthreads();

        // S = Q K^T
        f32x4 s[4];
        #pragma unroll
        for (int jf = 0; jf < 4; ++jf) {
            f32x4 z = {};
            short8 kf0 = *(const short8*)&Ks[SW(jf * 16 + lo, hi)];
            short8 kf1 = *(const short8*)&Ks[SW(jf * 16 + lo, 4 + hi)];
            z = __builtin_amdgcn_mfma_f32_16x16x32_bf16(qf0, kf0, z, 0, 0, 0);
            z = __builtin_amdgcn_mfma_f32_16x16x32_bf16(qf1, kf1, z, 0, 0, 0);
            s[jf] = z;
        }
        // scale + OR modifications
        if (orMode) {
            #pragma unroll
            for (int jf = 0; jf < 4; ++jf) {
                #pragma unroll
                for (int r = 0; r < 4; ++r) {
                    int ig = i0 + w * 16 + hi * 4 + r;
                    int jg = j0 + jf * 16 + lo;
                    float av = alphaT[((size_t)b << 20) + ((size_t)ig << 10) + jg];
                    float sv = s[jf][r] * 0.125f * (1.0f - av);
                    if (ig == jg) sv = 0.0f;
                    s[jf][r] = sv;
                }
            }
        } else {
            #pragma unroll
            for (int jf = 0; jf < 4; ++jf)
                #pragma unroll
                for (int r = 0; r < 4; ++r) s[jf][r] *= 0.125f;
        }
        // deferred-max online softmax (T13): slow path is rare
        float mx4[4];
        #pragma unroll
        for (int r = 0; r < 4; ++r)
            mx4[r] = fmaxf(fmaxf(s[0][r], s[1][r]), fmaxf(s[2][r], s[3][r]));
        float need = fmaxf(fmaxf(mx4[0] - m_r[0], mx4[1] - m_r[1]),
                           fmaxf(mx4[2] - m_r[2], mx4[3] - m_r[3]));
        if (!__all(need <= 8.0f)) {
            #pragma unroll
            for (int r = 0; r < 4; ++r) {
                float mx = mx4[r];
                #pragma unroll
                for (int msk = 8; msk >= 1; msk >>= 1) mx = fmaxf(mx, __shfl_xor(mx, msk));
                float mn = fmaxf(m_r[r], mx);
                float scl = __expf(m_r[r] - mn);
                m_r[r] = mn;
                l_r[r] *= scl;
                #pragma unroll
                for (int df = 0; df < 4; ++df) o[df][r] *= scl;
            }
        }
        #pragma unroll
        for (int r = 0; r < 4; ++r) {
            #pragma unroll
            for (int jf = 0; jf < 4; ++jf) {
                float p = __expf(s[jf][r] - m_r[r]);
                s[jf][r] = p;
                l_r[r] += p;
            }
        }
        // P -> LDS (bf16, swizzled, per-warp region)
        #pragma unroll
        for (int jf = 0; jf < 4; ++jf)
            #pragma unroll
            for (int r = 0; r < 4; ++r) {
                int row = hi * 4 + r;
                Ps[w * 1024 + row * 64 + ((jf * 16 + lo) ^ ((row & 7) * 8))] = f2bf(s[jf][r]);
            }
        // O += P V  (V rows are d, k is j)
        short8 pa0 = *(const short8*)&Ps[w * 1024 + SW(lo, hi)];
        short8 pa1 = *(const short8*)&Ps[w * 1024 + SW(lo, 4 + hi)];
        #pragma unroll
        for (int df = 0; df < 4; ++df) {
            short8 v0 = *(const short8*)&Vs[SW(df * 16 + lo, hi)];
            short8 v1 = *(const short8*)&Vs[SW(df * 16 + lo, 4 + hi)];
            o[df] = __builtin_amdgcn_mfma_f32_16x16x32_bf16(pa0, v0, o[df], 0, 0, 0);
            o[df] = __builtin_amdgcn_mfma_f32_16x16x32_bf16(pa1, v1, o[df], 0, 0, 0);
        }
        __syncthreads();
    }
    // final cross-lane sum of l partials, then write
    #pragma unroll
    for (int r = 0; r < 4; ++r) {
        float ls = l_r[r];
        #pragma unroll
        for (int msk = 8; msk >= 1; msk >>= 1) ls += __shfl_xor(ls, msk);
        l_r[r] = 1.0f / ls;
    }
    #pragma unroll
    for (int df = 0; df < 4; ++df) {
        #pragma unroll
        for (int r = 0; r < 4; ++r) {
            int ig = i0 + w * 16 + hi * 4 + r;
            out[((size_t)b * 1024 + ig) * 512 + h * 64 + df * 16 + lo] = f2bf(o[df][r] * l_r[r]);
        }
    }
}

extern "C" void kernel_launch(void* const* d_in, const int* in_sizes, int n_in,
                              void* d_out, int out_size, void* d_ws, size_t ws_size,
                              hipStream_t stream)
{
    const float* x     = (const float*)d_in[0];
    const float* orqy  = (const float*)d_in[1];
    const float* alpha = (const float*)d_in[2];
    const float* ln_w  = (const float*)d_in[3];
    const float* ln_b  = (const float*)d_in[4];
    const float* w_qkv = (const float*)d_in[5];
    const float* w_orq = (const float*)d_in[6];
    const float* w_out = (const float*)d_in[7];
    float* outp = (float*)d_out;

    char* base = (char*)d_ws;
    size_t off = 0;
    auto alloc = [&](size_t bytes) -> char* {
        char* r = base + off;
        off += (bytes + 255) & ~(size_t)255;
        return r;
    };
    const size_t RC = 8192ull * 512 * 2; // one [8192,512] bf16 buffer
    u16* xn       = (u16*)alloc(RC);
    u16* orqn     = (u16*)alloc(RC);
    u16* qb       = (u16*)alloc(RC);
    u16* kb       = (u16*)alloc(RC);
    u16* vb       = (u16*)alloc(RC);   // stored transposed [bh][64][1024]
    u16* orqb     = (u16*)alloc(RC);
    u16* attout   = (u16*)alloc(RC);
    u16* orattout = (u16*)alloc(RC);
    u16* wqkvT    = (u16*)alloc(1536ull * 512 * 2);
    u16* worqT    = (u16*)alloc(512ull * 512 * 2);
    u16* woutT    = (u16*)alloc(512ull * 512 * 2);
    float* alphaT = (float*)alloc(8ull * 1024 * 1024 * 4);

    wtrans_kernel<<<dim3(48, 16), 256, 0, stream>>>(w_qkv, wqkvT, 512, 1536);
    wtrans_kernel<<<dim3(16, 16), 256, 0, stream>>>(w_orq, worqT, 512, 512);
    wtrans_kernel<<<dim3(16, 16), 256, 0, stream>>>(w_out, woutT, 512, 512);
    atrans_kernel<<<dim3(32, 32, 8), 256, 0, stream>>>(alpha, alphaT);
    ln_kernel<<<4096, 256, 0, stream>>>(x, orqy, ln_w, ln_b, xn, orqn);
    gemm_kernel<<<dim3(12, 64), 256, 0, stream>>>(xn, wqkvT, 1536, 512, 0, qb, kb, vb, nullptr);
    gemm_kernel<<<dim3(4, 64), 256, 0, stream>>>(orqn, worqT, 512, 512, 1, orqb, nullptr, nullptr, nullptr);
    attn_kernel<<<dim3(1024), 256, 0, stream>>>(qb, kb, vb, nullptr, attout, 0);
    attn_kernel<<<dim3(1024), 256, 0, stream>>>(orqb, kb, vb, alphaT, orattout, 1);
    gemm_kernel<<<dim3(4, 64), 256, 0, stream>>>(attout, woutT, 512, 512, 2, nullptr, nullptr, nullptr, outp);
    gemm_kernel<<<dim3(4, 64), 256, 0, stream>>>(orattout, woutT, 512, 512, 2, nullptr, nullptr, nullptr, outp + 8ull * 1024 * 512);
}